// Round 8
// baseline (277.029 us; speedup 1.0000x reference)
//
#include <hip/hip_runtime.h>
#include <hip/hip_bf16.h>
#include <math.h>

// SphConv: B=64, n=32, C_in=C_out=128, L=16, (l,m) pairs l>=m: 136.
// No d_ws (size unknown). Intermediates packed inside d_out; every k_bwd
// block's read-set lies inside its own output region. dtype (fp32 vs bf16)
// detected from data (deterministic -> graph-safe).

#define NPAIR 136

static __device__ __forceinline__ float us2f(unsigned short u) {
  union { unsigned int i; float f; } v; v.i = ((unsigned int)u) << 16; return v.f;
}
static __device__ __forceinline__ unsigned short f2us(float f) {
  __hip_bfloat16 h = __float2bfloat16(f);
  return *(unsigned short*)&h;
}
static __device__ __forceinline__ float lo_f(unsigned int pk) {
  union { unsigned int i; float f; } v; v.i = pk << 16; return v.f;
}
static __device__ __forceinline__ float hi_f(unsigned int pk) {
  union { unsigned int i; float f; } v; v.i = pk & 0xffff0000u; return v.f;
}

__device__ __align__(16) unsigned short g_atab_h[NPAIR * 32]; // bf16 Q*wj
__device__ __align__(16) float          g_stab[NPAIR * 32];   // fp32 Q*scale*(m?2:1)

static __device__ __forceinline__ int detect_fp32(const void* xin) {
  const unsigned short* u = (const unsigned short*)xin;
  int lane = threadIdx.x & 63;
  int big = 0;
#pragma unroll
  for (int q = 0; q < 4; ++q) {
    float v = us2f(u[lane * 8 + q * 2]);
    if (!(fabsf(v) <= 1e3f)) big = 1;
  }
  unsigned long long mask = __ballot(big);
  return (__popcll(mask) >= 16) ? 1 : 0;
}

// Scratch-in-d_out addressing (unchanged from rounds 5/6).
static __device__ __forceinline__ size_t chunk_base(int b, int rq, int s, int esz) {
  return ((size_t)b * 131072 + (size_t)s * 128 + rq * 32) * (size_t)esz;
}
static __device__ __forceinline__ size_t chat_addr(int b, int o, int pair, int rr, int esz) {
  int u = (pair * 32 + (o & 31)) * 2 + rr;
  int fs = 8 * esz;
  return chunk_base(b, o >> 5, u / fs, esz) + (size_t)(u % fs) * 4;
}
static __device__ __forceinline__ size_t chat_addr_lin(int b, int rq, int u, int esz) {
  int fs = 8 * esz;
  return chunk_base(b, rq, u / fs, esz) + (size_t)(u % fs) * 4;
}
static __device__ __forceinline__ size_t coef_addr(int b, int c, int pair, int esz) {
  int w = pair * 128 + c;
  int rq = w / 4352, wr = w % 4352;
  int s0 = (esz == 4) ? 272 : 544;
  return chunk_base(b, rq, s0 + (wr >> 4), esz) + (size_t)(wr & 15) * (2 * esz);
}

// 32-pt DFT trig tables, cos/sin(2*pi*k/32)
#define DEF_TRIG \
  constexpr float CT[32] = { \
    1.0f, 0.98078528f, 0.92387953f, 0.83146961f, 0.70710678f, 0.55557023f, \
    0.38268343f, 0.19509032f, 0.0f, -0.19509032f, -0.38268343f, -0.55557023f, \
    -0.70710678f, -0.83146961f, -0.92387953f, -0.98078528f, -1.0f, \
    -0.98078528f, -0.92387953f, -0.83146961f, -0.70710678f, -0.55557023f, \
    -0.38268343f, -0.19509032f, 0.0f, 0.19509032f, 0.38268343f, 0.55557023f, \
    0.70710678f, 0.83146961f, 0.92387953f, 0.98078528f }; \
  constexpr float ST[32] = { \
    0.0f, 0.19509032f, 0.38268343f, 0.55557023f, 0.70710678f, 0.83146961f, \
    0.92387953f, 0.98078528f, 1.0f, 0.98078528f, 0.92387953f, 0.83146961f, \
    0.70710678f, 0.55557023f, 0.38268343f, 0.19509032f, 0.0f, \
    -0.19509032f, -0.38268343f, -0.55557023f, -0.70710678f, -0.83146961f, \
    -0.92387953f, -0.98078528f, -1.0f, -0.98078528f, -0.92387953f, \
    -0.83146961f, -0.70710678f, -0.55557023f, -0.38268343f, -0.19509032f }

// ---------------------------------------------------------------------------
// K0: tables. One block per (l,m) pair x 32 j — short f64 chains.
// ---------------------------------------------------------------------------
__global__ void k_init() {
  const int pair = blockIdx.x, j = threadIdx.x;
  int m = 0;
#pragma unroll
  for (int mm = 1; mm < 16; ++mm) {
    int off = mm * 16 - (mm * (mm - 1)) / 2;
    if (off <= pair) m = mm;
  }
  const int l = m + (pair - (m * 16 - (m * (m - 1)) / 2));
  double theta = M_PI * (j + 0.5) / 32.0;
  double x = cos(theta), sx = sin(theta);
  double wj = sx * (M_PI / 32.0) * (2.0 * M_PI / 32.0);
  double pmm = 1.0;
  for (int k = 1; k <= m; ++k) pmm *= -(2.0 * k - 1.0) * sx;
  double p = pmm, pl1 = 0.0, pl2 = 0.0;
  for (int ll = m; ll <= l; ++ll) {
    if (ll == m)          p = pmm;
    else if (ll == m + 1) p = (2.0 * m + 1.0) * x * pmm;
    else                  p = ((2.0 * ll - 1.0) * x * pl1 - (double)(ll + m - 1) * pl2) / (double)(ll - m);
    pl2 = pl1; pl1 = p;
  }
  double r = 1.0;
  for (int k = l - m + 1; k <= l + m; ++k) r *= (double)k;   // (l+m)!/(l-m)!
  double Nlm = sqrt((2.0 * l + 1.0) / (4.0 * M_PI) / r);
  g_atab_h[pair * 32 + j] = f2us((float)(Nlm * p * wj));
  g_stab[pair * 32 + j] = (float)(Nlm * p * (2.0 * M_PI * sqrt(4.0 * M_PI / (2.0 * l + 1.0)))
                                  * (m ? 2.0 : 1.0));
}

// ---------------------------------------------------------------------------
// K1: fused FFT(phi) + Legendre analysis -> coef. Block=(b, 4-ch group),
// XCD-swizzled. Register-lean phases; VGPR cap 128 (4 waves/SIMD).
// ---------------------------------------------------------------------------
__global__ __launch_bounds__(256, 4) void k_fwd(const void* __restrict__ xin,
                                                char* __restrict__ outbuf) {
  const int fp32m = detect_fp32(xin);
  const int esz = fp32m ? 4 : 2;
  __shared__ __align__(16) unsigned short xs[32 * 132];   // [p][j*4+c]
  __shared__ __align__(16) unsigned int   fsp[64 * 36];   // [(m*4+c)][j] re|im bf16
  __shared__ __align__(16) unsigned short at[NPAIR * 40]; // atab bf16, row pad 40
  const int blk = blockIdx.x;
  const int b = (blk & 7) | (((blk >> 8) & 7) << 3);      // same-b -> same XCD
  const int cq = (blk >> 3) & 31;
  const int t = threadIdx.x;
  for (int i = t; i < NPAIR * 4; i += 256) {              // FIX: all 4 uint4/row
    int pair = i >> 2, q = i & 3;
    *(uint4*)&at[pair * 40 + q * 8] =
        *(const uint4*)&g_atab_h[pair * 32 + q * 8];
  }
  if (fp32m) {
    const float* xf = (const float*)xin;
#pragma unroll
    for (int it = 0; it < 4; ++it) {
      int s = t + it * 256, j = s >> 5, p = s & 31;
      float4 v = *(const float4*)(xf + ((size_t)b * 1024 + s) * 128 + cq * 4);
      unsigned int lo = (unsigned int)f2us(v.x) | ((unsigned int)f2us(v.y) << 16);
      unsigned int hi = (unsigned int)f2us(v.z) | ((unsigned int)f2us(v.w) << 16);
      *(uint2*)&xs[p * 132 + j * 4] = make_uint2(lo, hi);
    }
  } else {
    const unsigned short* xh = (const unsigned short*)xin;
#pragma unroll
    for (int it = 0; it < 4; ++it) {
      int s = t + it * 256, j = s >> 5, p = s & 31;
      uint2 v = *(const uint2*)(xh + ((size_t)b * 1024 + s) * 128 + cq * 4);
      *(uint2*)&xs[p * 132 + j * 4] = v;
    }
  }
  __syncthreads();
  {   // phase 1: 32-pt real DFT; thread=(mh, c, j). Live: sp16+dm16+x0+x16.
    const int mh = t & 1, c = (t >> 1) & 3, j = t >> 3;
    const int rb = j * 4 + c;
    float x0  = us2f(xs[rb]);
    float x16 = us2f(xs[16 * 132 + rb]);
    float sp[16], dm[16];
#pragma unroll
    for (int p = 1; p <= 15; ++p) {
      float a = us2f(xs[p * 132 + rb]);
      float bq = us2f(xs[(32 - p) * 132 + rb]);
      sp[p] = a + bq; dm[p] = a - bq;
    }
    DEF_TRIG;
#pragma unroll
    for (int mi = 0; mi < 8; ++mi) {
      int m = mh * 8 + mi;
      float re = x0 + ((m & 1) ? -x16 : x16);
      float im = 0.f;
#pragma unroll
      for (int p = 1; p <= 15; ++p) {
        re += sp[p] * CT[(m * p) & 31];
        im -= dm[p] * ST[(m * p) & 31];
      }
      fsp[(m * 4 + c) * 36 + j] = (unsigned int)f2us(re) | ((unsigned int)f2us(im) << 16);
    }
  }
  __syncthreads();
  {   // phase 2: quadrature -> coef. j-slices outer, l inner; 8 accumulators.
    const int m3 = t >> 4, cc = (t >> 2) & 3, lp = t & 3;
    const int c = cq * 4 + cc;
    const int base = m3 * 16 - (m3 * (m3 - 1)) / 2;
    int pl[4];
#pragma unroll
    for (int k = 0; k < 4; ++k) {
      int l = m3 + lp + 4 * k;
      pl[k] = (l < 16) ? (base + (l - m3)) : 0;
    }
    float sr[4] = {0.f,0.f,0.f,0.f}, si[4] = {0.f,0.f,0.f,0.f};
    const unsigned int* frow = &fsp[(m3 * 4 + cc) * 36];
#pragma unroll
    for (int q8 = 0; q8 < 4; ++q8) {          // slice of 8 j
      uint4 u0 = *(const uint4*)&frow[q8 * 8];
      uint4 u1 = *(const uint4*)&frow[q8 * 8 + 4];
      float fr0 = lo_f(u0.x), fi0 = hi_f(u0.x), fr1 = lo_f(u0.y), fi1 = hi_f(u0.y);
      float fr2 = lo_f(u0.z), fi2 = hi_f(u0.z), fr3 = lo_f(u0.w), fi3 = hi_f(u0.w);
      float fr4 = lo_f(u1.x), fi4 = hi_f(u1.x), fr5 = lo_f(u1.y), fi5 = hi_f(u1.y);
      float fr6 = lo_f(u1.z), fi6 = hi_f(u1.z), fr7 = lo_f(u1.w), fi7 = hi_f(u1.w);
#pragma unroll
      for (int k = 0; k < 4; ++k) {
        uint4 a4 = *(const uint4*)&at[pl[k] * 40 + q8 * 8];
        unsigned int ax = a4.x, ay = a4.y, az = a4.z, aw = a4.w;
        float a0 = us2f((unsigned short)(ax & 0xffff)), a1 = us2f((unsigned short)(ax >> 16));
        float a2 = us2f((unsigned short)(ay & 0xffff)), a3 = us2f((unsigned short)(ay >> 16));
        float a4f = us2f((unsigned short)(az & 0xffff)), a5 = us2f((unsigned short)(az >> 16));
        float a6 = us2f((unsigned short)(aw & 0xffff)), a7 = us2f((unsigned short)(aw >> 16));
        sr[k] += a0*fr0 + a1*fr1 + a2*fr2 + a3*fr3 + a4f*fr4 + a5*fr5 + a6*fr6 + a7*fr7;
        si[k] += a0*fi0 + a1*fi1 + a2*fi2 + a3*fi3 + a4f*fi4 + a5*fi5 + a6*fi6 + a7*fi7;
      }
    }
#pragma unroll
    for (int k = 0; k < 4; ++k) {
      int l = m3 + lp + 4 * k;
      if (l < 16) {
        size_t ad = coef_addr(b, c, pl[k], esz);
        if (fp32m) *(float2*)(outbuf + ad) = make_float2(sr[k], si[k]);
        else *(unsigned int*)(outbuf + ad) =
               (unsigned int)f2us(sr[k]) | ((unsigned int)f2us(si[k]) << 16);
      }
    }
  }
}

// ---------------------------------------------------------------------------
// K2: channel GEMM. Block=(pair, rr, b-half, o-half): M=32(b),N=64(o),K=128.
// 1088 blocks x 256 thr.
// ---------------------------------------------------------------------------
__global__ __launch_bounds__(256, 2) void k_chan(char* __restrict__ outbuf,
                                                 const void* __restrict__ Wv,
                                                 const void* __restrict__ xin) {
  const int fp32m = detect_fp32(xin);
  const int esz = fp32m ? 4 : 2;
  const int pair = blockIdx.x >> 3;
  const int rr = (blockIdx.x >> 2) & 1, bh = (blockIdx.x >> 1) & 1, otile = blockIdx.x & 1;
  int m = 0;
#pragma unroll
  for (int mm = 1; mm < 16; ++mm) {
    int off = mm * 16 - (mm * (mm - 1)) / 2;
    if (off <= pair) m = mm;
  }
  const int l = m + (pair - (m * 16 - (m * (m - 1)) / 2));
  __shared__ float Xs[32 * 132];                 // [b'][c]
  __shared__ __align__(16) float Wsh[32 * 68];   // [kk][o]
  const int t = threadIdx.x;
  for (int i = t; i < 4096; i += 256) {
    int bb = bh * 32 + (i >> 7), c = i & 127;
    size_t ad = coef_addr(bb, c, pair, esz);
    float v;
    if (fp32m) v = ((const float*)(outbuf + ad))[rr];
    else {
      unsigned int pk = *(const unsigned int*)(outbuf + ad);
      v = rr ? hi_f(pk) : lo_f(pk);
    }
    Xs[(i >> 7) * 132 + c] = v;
  }
  const int tx = t & 15, ty = t >> 4;
  float acc[2][4] = {};
  for (int kc = 0; kc < 4; ++kc) {
    __syncthreads();
    {
      int o = t & 63, k0 = t >> 6;
#pragma unroll
      for (int it = 0; it < 8; ++it) {
        int kk = k0 + it * 4;
        size_t widx = (size_t)(kc * 32 + kk) * 2048 + l * 128 + otile * 64 + o;
        Wsh[kk * 68 + o] = fp32m ? ((const float*)Wv)[widx]
                                 : us2f(((const unsigned short*)Wv)[widx]);
      }
    }
    __syncthreads();
#pragma unroll
    for (int k = 0; k < 32; ++k) {
      float a0 = Xs[(ty * 2 + 0) * 132 + kc * 32 + k];
      float a1 = Xs[(ty * 2 + 1) * 132 + kc * 32 + k];
      float4 w = *(const float4*)&Wsh[k * 68 + tx * 4];
      acc[0][0] += a0*w.x; acc[0][1] += a0*w.y; acc[0][2] += a0*w.z; acc[0][3] += a0*w.w;
      acc[1][0] += a1*w.x; acc[1][1] += a1*w.y; acc[1][2] += a1*w.z; acc[1][3] += a1*w.w;
    }
  }
#pragma unroll
  for (int r = 0; r < 2; ++r) {
    int bb = bh * 32 + ty * 2 + r;
#pragma unroll
    for (int u4 = 0; u4 < 4; ++u4) {
      int o = otile * 64 + tx * 4 + u4;
      *(float*)(outbuf + chat_addr(bb, o, pair, rr, esz)) = acc[r][u4];
    }
  }
}

// ---------------------------------------------------------------------------
// K3: fused Legendre synthesis + inverse DFT + bias.
// Block=(b, oq of 32 out-ch), 512 thr=(jh of 16 -> 2 j, ol of 32).
// Barrier-free after staging; phase-B twiddles via register recurrence.
// ---------------------------------------------------------------------------
__global__ __launch_bounds__(512, 1) void k_bwd(char* __restrict__ outbuf,
                                                const void* __restrict__ biasv,
                                                const void* __restrict__ xin) {
  const int fp32m = detect_fp32(xin);
  const int esz = fp32m ? 4 : 2;
  __shared__ float chs[NPAIR * 64];                 // [(pair*32+ol)*2+rr]
  __shared__ __align__(16) float stb[NPAIR * 32];   // [pair][j]
  const int b = blockIdx.x >> 2, oq = blockIdx.x & 3;
  const int t = threadIdx.x;
  for (int u = t; u < NPAIR * 64; u += 512)
    chs[u] = *(const float*)(outbuf + chat_addr_lin(b, oq, u, esz));
  for (int i = t; i < NPAIR * 32; i += 512) stb[i] = g_stab[i];
  const int jh = t >> 5, ol = t & 31, o = oq * 32 + ol, j0 = jh * 2;
  float bias_v = fp32m ? ((const float*)biasv)[o]
                       : us2f(((const unsigned short*)biasv)[o]);
  __syncthreads();

  // phase A: G[m] for j0, j0+1
  float Gr0[16], Gi0[16], Gr1[16], Gi1[16];
#pragma unroll
  for (int m = 0; m < 16; ++m) { Gr0[m]=0.f; Gi0[m]=0.f; Gr1[m]=0.f; Gi1[m]=0.f; }
  int pair = 0;
#pragma unroll
  for (int m = 0; m < 16; ++m) {
#pragma unroll
    for (int l = m; l < 16; ++l) {
      float2 s2 = *(const float2*)&stb[pair * 32 + j0];
      float2 cv = *(const float2*)&chs[(pair * 32 + ol) * 2];
      Gr0[m] += s2.x * cv.x; Gi0[m] += s2.x * cv.y;
      Gr1[m] += s2.y * cv.x; Gi1[m] += s2.y * cv.y;
      ++pair;
    }
  }
  // phase B: inverse DFT via per-m twiddle recurrence, p<->32-p symmetry
  DEF_TRIG;
  float twr[16], twi[16];
#pragma unroll
  for (int m = 0; m < 16; ++m) { twr[m] = 1.f; twi[m] = 0.f; }
  for (int pp = 0; pp <= 16; ++pp) {
    float A0=0.f,A1=0.f,B0=0.f,B1=0.f;
#pragma unroll
    for (int m = 0; m < 16; ++m) {
      A0 += Gr0[m] * twr[m]; A1 += Gr1[m] * twr[m];
      B0 += Gi0[m] * twi[m]; B1 += Gi1[m] * twi[m];
      float nr = twr[m] * CT[m] - twi[m] * ST[m];
      float ni = twi[m] * CT[m] + twr[m] * ST[m];
      twr[m] = nr; twi[m] = ni;
    }
    int p2 = (32 - pp) & 31;
    float va[2] = { bias_v + A0 - B0, bias_v + A1 - B1 };
    float vb[2] = { bias_v + A0 + B0, bias_v + A1 + B1 };
#pragma unroll
    for (int jj = 0; jj < 2; ++jj) {
      size_t E = ((size_t)(b * 32 + j0 + jj) * 32) * 128 + o;
      if (fp32m) {
        ((float*)outbuf)[E + (size_t)pp * 128] = va[jj];
        ((float*)outbuf)[E + (size_t)p2 * 128] = vb[jj];
      } else {
        ((unsigned short*)outbuf)[E + (size_t)pp * 128] = f2us(va[jj]);
        ((unsigned short*)outbuf)[E + (size_t)p2 * 128] = f2us(vb[jj]);
      }
    }
  }
}

// ---------------------------------------------------------------------------
extern "C" void kernel_launch(void* const* d_in, const int* in_sizes, int n_in,
                              void* d_out, int out_size, void* d_ws, size_t ws_size,
                              hipStream_t stream) {
  const void* xin  = d_in[0];   // (64,32,32,128) fp32 or bf16 (auto-detected)
  const void* W    = d_in[1];   // (128,16,128)
  const void* bias = d_in[2];   // (128)
  char* out = (char*)d_out;

  hipLaunchKernelGGL(k_init, dim3(NPAIR), dim3(32),  0, stream);
  hipLaunchKernelGGL(k_fwd,  dim3(2048),  dim3(256), 0, stream, xin, out);
  hipLaunchKernelGGL(k_chan, dim3(1088),  dim3(256), 0, stream, out, W, xin);
  hipLaunchKernelGGL(k_bwd,  dim3(256),   dim3(512), 0, stream, out, bias, xin);
}

// Round 9
// 214.199 us; speedup vs baseline: 1.2933x; 1.2933x over previous
//
#include <hip/hip_runtime.h>
#include <hip/hip_bf16.h>
#include <math.h>

// SphConv: B=64, n=32, C_in=C_out=128, L=16, (l,m) pairs l>=m: 136.
// Intermediates packed inside d_out in 128-B-contiguous chunks:
//  per b, per p-row s (= j*32+p) and o-half: chunk = 32 uints at
//  ((b*131072 + s*128 + half*64)*esz). chat(b,oh): chunks s in [0,272);
//  coef(b,h): chunks s in [272,544). k_bwd block (b,oh) writes its entire
//  comb, and reads only chat(b,oh) -> read-set inside own write region.

#define NPAIR 136

static __device__ __forceinline__ float us2f(unsigned int u) {
  union { unsigned int i; float f; } v; v.i = u << 16; return v.f;
}
static __device__ __forceinline__ unsigned short f2us(float f) {
  __hip_bfloat16 h = __float2bfloat16(f);
  return *(unsigned short*)&h;
}
static __device__ __forceinline__ float lo_f(unsigned int pk) {
  union { unsigned int i; float f; } v; v.i = pk << 16; return v.f;
}
static __device__ __forceinline__ float hi_f(unsigned int pk) {
  union { unsigned int i; float f; } v; v.i = pk & 0xffff0000u; return v.f;
}
static __device__ __forceinline__ unsigned int packbf(float a, float b) {
  return (unsigned int)f2us(a) | ((unsigned int)f2us(b) << 16);
}

__device__ __align__(16) unsigned short g_atab_h[NPAIR * 32]; // bf16 Q*wj
__device__ __align__(16) float          g_stab[NPAIR * 32];   // fp32 Q*scale*(m?2:1)

static __device__ __forceinline__ int detect_fp32(const void* xin) {
  const unsigned short* u = (const unsigned short*)xin;
  int lane = threadIdx.x & 63;
  int big = 0;
#pragma unroll
  for (int q = 0; q < 4; ++q) {
    float v = us2f((unsigned int)u[lane * 8 + q * 2]);
    if (!(fabsf(v) <= 1e3f)) big = 1;
  }
  unsigned long long mask = __ballot(big);
  return (__popcll(mask) >= 16) ? 1 : 0;
}

// chunk byte address: b region, p-row s, o-half, uint slot w
static __device__ __forceinline__ size_t comb_byte(int b, int s, int half, int esz, int w) {
  return ((size_t)b * 131072 + (size_t)s * 128 + half * 64) * (size_t)esz + (size_t)w * 4;
}
// chat(b,oh): payload uint u = pair*64 + ol (ol in [0,64))
static __device__ __forceinline__ size_t chat_byte(int b, int oh, int u, int esz) {
  return comb_byte(b, u >> 5, oh, esz, u & 31);
}
// coef(b,h): payload uint u = pair*64 + cl (cl in [0,64))
static __device__ __forceinline__ size_t coef_byte(int b, int h, int u, int esz) {
  return comb_byte(b, 272 + (u >> 5), h, esz, u & 31);
}

// 32-pt DFT trig tables, cos/sin(2*pi*k/32) — used with compile-time indices
#define DEF_TRIG \
  constexpr float CT[32] = { \
    1.0f, 0.98078528f, 0.92387953f, 0.83146961f, 0.70710678f, 0.55557023f, \
    0.38268343f, 0.19509032f, 0.0f, -0.19509032f, -0.38268343f, -0.55557023f, \
    -0.70710678f, -0.83146961f, -0.92387953f, -0.98078528f, -1.0f, \
    -0.98078528f, -0.92387953f, -0.83146961f, -0.70710678f, -0.55557023f, \
    -0.38268343f, -0.19509032f, 0.0f, 0.19509032f, 0.38268343f, 0.55557023f, \
    0.70710678f, 0.83146961f, 0.92387953f, 0.98078528f }; \
  constexpr float ST[32] = { \
    0.0f, 0.19509032f, 0.38268343f, 0.55557023f, 0.70710678f, 0.83146961f, \
    0.92387953f, 0.98078528f, 1.0f, 0.98078528f, 0.92387953f, 0.83146961f, \
    0.70710678f, 0.55557023f, 0.38268343f, 0.19509032f, 0.0f, \
    -0.19509032f, -0.38268343f, -0.55557023f, -0.70710678f, -0.83146961f, \
    -0.92387953f, -0.98078528f, -1.0f, -0.98078528f, -0.92387953f, \
    -0.83146961f, -0.70710678f, -0.55557023f, -0.38268343f, -0.19509032f }

// ---------------------------------------------------------------------------
// K0: tables. One block per (l,m) pair x 32 j.
// ---------------------------------------------------------------------------
__global__ void k_init() {
  const int pair = blockIdx.x, j = threadIdx.x;
  int m = 0;
#pragma unroll
  for (int mm = 1; mm < 16; ++mm) {
    int off = mm * 16 - (mm * (mm - 1)) / 2;
    if (off <= pair) m = mm;
  }
  const int l = m + (pair - (m * 16 - (m * (m - 1)) / 2));
  double theta = M_PI * (j + 0.5) / 32.0;
  double x = cos(theta), sx = sin(theta);
  double wj = sx * (M_PI / 32.0) * (2.0 * M_PI / 32.0);
  double pmm = 1.0;
  for (int k = 1; k <= m; ++k) pmm *= -(2.0 * k - 1.0) * sx;
  double p = pmm, pl1 = 0.0, pl2 = 0.0;
  for (int ll = m; ll <= l; ++ll) {
    if (ll == m)          p = pmm;
    else if (ll == m + 1) p = (2.0 * m + 1.0) * x * pmm;
    else                  p = ((2.0 * ll - 1.0) * x * pl1 - (double)(ll + m - 1) * pl2) / (double)(ll - m);
    pl2 = pl1; pl1 = p;
  }
  double r = 1.0;
  for (int k = l - m + 1; k <= l + m; ++k) r *= (double)k;   // (l+m)!/(l-m)!
  double Nlm = sqrt((2.0 * l + 1.0) / (4.0 * M_PI) / r);
  g_atab_h[pair * 32 + j] = f2us((float)(Nlm * p * wj));
  g_stab[pair * 32 + j] = (float)(Nlm * p * (2.0 * M_PI * sqrt(4.0 * M_PI / (2.0 * l + 1.0)))
                                  * (m ? 2.0 : 1.0));
}

// ---------------------------------------------------------------------------
// K1: fused FFT(phi) + Legendre analysis -> coef. Block=(b, 16 channels),
// 512 blocks, XCD-swizzled (8 cq-blocks of one b share an XCD).
// Phase 1: compile-time m (trig folds to literals, no dynamic indexing).
// Phase 2: F resident as 8 packed uint4; per-l broadcast atab reads.
// ---------------------------------------------------------------------------
__global__ __launch_bounds__(256) void k_fwd(const void* __restrict__ xin,
                                             char* __restrict__ outbuf) {
  const int fp32m = detect_fp32(xin);
  const int esz = fp32m ? 4 : 2;
  __shared__ __align__(16) unsigned short xs[32 * 520];    // [p][j*16+c]
  __shared__ __align__(16) unsigned int   fsp[256 * 36];   // [(m*16+c)][j] re|im bf16
  __shared__ __align__(16) unsigned short at[NPAIR * 32];  // atab bf16
  const int blk = blockIdx.x;
  const int b = (blk & 7) | ((blk >> 6) << 3);             // same-b -> same XCD
  const int cq = (blk >> 3) & 7;                           // 16-channel group
  const int t = threadIdx.x;
  for (int i = t; i < NPAIR * 32 / 8; i += 256)            // 544 x uint4
    ((uint4*)at)[i] = ((const uint4*)g_atab_h)[i];
  if (fp32m) {
    const float* xf = (const float*)xin;
#pragma unroll
    for (int it = 0; it < 16; ++it) {
      int i = t + it * 256;                                // [0,4096)
      int jp = i >> 2, q = i & 3;
      float4 v = *(const float4*)(xf + ((size_t)b * 1024 + jp) * 128 + cq * 16 + q * 4);
      int p = jp & 31, j = jp >> 5;
      *(uint2*)&xs[p * 520 + j * 16 + q * 4] =
          make_uint2(packbf(v.x, v.y), packbf(v.z, v.w));
    }
  } else {
    const unsigned short* xh = (const unsigned short*)xin;
#pragma unroll
    for (int it = 0; it < 8; ++it) {
      int i = t + it * 256;                                // [0,2048)
      int jp = i >> 1, hf = i & 1;
      uint4 v = *(const uint4*)(xh + ((size_t)b * 1024 + jp) * 128 + cq * 16 + hf * 8);
      int p = jp & 31, j = jp >> 5;
      *(uint4*)&xs[p * 520 + j * 16 + hf * 8] = v;
    }
  }
  __syncthreads();
  {   // phase 1: 32-pt real DFT. Two (j,c) tasks per thread; m compile-time.
    DEF_TRIG;
    for (int task = t; task < 512; task += 256) {
      const int j = task >> 4, c = task & 15, rb = j * 16 + c;
      float x0  = us2f((unsigned int)xs[rb]);
      float x16 = us2f((unsigned int)xs[16 * 520 + rb]);
      float sp[16], dm[16];
#pragma unroll
      for (int p = 1; p <= 15; ++p) {
        float a  = us2f((unsigned int)xs[p * 520 + rb]);
        float bq = us2f((unsigned int)xs[(32 - p) * 520 + rb]);
        sp[p] = a + bq; dm[p] = a - bq;
      }
#pragma unroll
      for (int mi = 0; mi < 16; ++mi) {
        float re = x0 + ((mi & 1) ? -x16 : x16);
        float im = 0.f;
#pragma unroll
        for (int p = 1; p <= 15; ++p) {
          re += sp[p] * CT[(mi * p) & 31];
          im -= dm[p] * ST[(mi * p) & 31];
        }
        fsp[(mi * 16 + c) * 36 + j] = packbf(re, im);
      }
    }
  }
  __syncthreads();
  {   // phase 2: quadrature -> coef. Thread=(m,c); F packed-resident.
    const int m = t >> 4, c = t & 15;
    const int cg = cq * 16 + c, h = cg >> 6, cl = cg & 63;
    const int base = m * 16 - (m * (m - 1)) / 2;
    uint4 F[8];
#pragma unroll
    for (int q = 0; q < 8; ++q) F[q] = *(const uint4*)&fsp[(m * 16 + c) * 36 + q * 4];
    for (int l = m; l < 16; ++l) {
      int pair = base + (l - m);
      float sr = 0.f, si = 0.f;
#pragma unroll
      for (int q = 0; q < 4; ++q) {
        uint4 a = *(const uint4*)&at[pair * 32 + q * 8];   // 8 bf16 (broadcast)
        float a0 = us2f(a.x & 0xffff), a1 = us2f(a.x >> 16);
        float a2 = us2f(a.y & 0xffff), a3 = us2f(a.y >> 16);
        float a4 = us2f(a.z & 0xffff), a5 = us2f(a.z >> 16);
        float a6 = us2f(a.w & 0xffff), a7 = us2f(a.w >> 16);
        uint4 f0 = F[2 * q], f1 = F[2 * q + 1];
        sr += a0 * lo_f(f0.x) + a1 * lo_f(f0.y) + a2 * lo_f(f0.z) + a3 * lo_f(f0.w)
            + a4 * lo_f(f1.x) + a5 * lo_f(f1.y) + a6 * lo_f(f1.z) + a7 * lo_f(f1.w);
        si += a0 * hi_f(f0.x) + a1 * hi_f(f0.y) + a2 * hi_f(f0.z) + a3 * hi_f(f0.w)
            + a4 * hi_f(f1.x) + a5 * hi_f(f1.y) + a6 * hi_f(f1.z) + a7 * hi_f(f1.w);
      }
      int u = pair * 64 + cl;
      *(unsigned int*)(outbuf + coef_byte(b, h, u, esz)) = packbf(sr, si);
    }
  }
}

// ---------------------------------------------------------------------------
// K2: channel GEMM. Block=(pair, b-half, o-half): M=32(b), N=64(o), K=128(c),
// re+im together. 544 blocks x 256 thr.
// ---------------------------------------------------------------------------
__global__ __launch_bounds__(256) void k_chan(char* __restrict__ outbuf,
                                              const void* __restrict__ Wv,
                                              const void* __restrict__ xin) {
  const int fp32m = detect_fp32(xin);
  const int esz = fp32m ? 4 : 2;
  const int pair = blockIdx.x >> 2;
  const int bh = (blockIdx.x >> 1) & 1, otile = blockIdx.x & 1;
  int m = 0;
#pragma unroll
  for (int mm = 1; mm < 16; ++mm) {
    int off = mm * 16 - (mm * (mm - 1)) / 2;
    if (off <= pair) m = mm;
  }
  const int l = m + (pair - (m * 16 - (m * (m - 1)) / 2));
  __shared__ float Xr[32 * 132], Xi[32 * 132];   // [b'][c]
  __shared__ __align__(16) float Wsh[32 * 68];   // [kk][o]
  const int t = threadIdx.x;
  for (int i = t; i < 4096; i += 256) {
    int bl = i >> 7, c = i & 127;
    int u = pair * 64 + (c & 63), h = c >> 6;
    unsigned int pk = *(const unsigned int*)(outbuf + coef_byte(bh * 32 + bl, h, u, esz));
    Xr[bl * 132 + c] = lo_f(pk);
    Xi[bl * 132 + c] = hi_f(pk);
  }
  const int tx = t & 15, ty = t >> 4;
  float accR[2][4] = {}, accI[2][4] = {};
  for (int kc = 0; kc < 4; ++kc) {
    __syncthreads();
    {
      int o = t & 63, k0 = t >> 6;
#pragma unroll
      for (int it = 0; it < 8; ++it) {
        int kk = k0 + it * 4;
        size_t widx = (size_t)(kc * 32 + kk) * 2048 + l * 128 + otile * 64 + o;
        Wsh[kk * 68 + o] = fp32m ? ((const float*)Wv)[widx]
                                 : us2f((unsigned int)((const unsigned short*)Wv)[widx]);
      }
    }
    __syncthreads();
#pragma unroll
    for (int k = 0; k < 32; ++k) {
      int K = kc * 32 + k;
      float r0 = Xr[(ty * 2 + 0) * 132 + K], r1 = Xr[(ty * 2 + 1) * 132 + K];
      float i0 = Xi[(ty * 2 + 0) * 132 + K], i1 = Xi[(ty * 2 + 1) * 132 + K];
      float4 w = *(const float4*)&Wsh[k * 68 + tx * 4];
      accR[0][0] += r0*w.x; accR[0][1] += r0*w.y; accR[0][2] += r0*w.z; accR[0][3] += r0*w.w;
      accR[1][0] += r1*w.x; accR[1][1] += r1*w.y; accR[1][2] += r1*w.z; accR[1][3] += r1*w.w;
      accI[0][0] += i0*w.x; accI[0][1] += i0*w.y; accI[0][2] += i0*w.z; accI[0][3] += i0*w.w;
      accI[1][0] += i1*w.x; accI[1][1] += i1*w.y; accI[1][2] += i1*w.z; accI[1][3] += i1*w.w;
    }
  }
#pragma unroll
  for (int r = 0; r < 2; ++r) {
    int bb = bh * 32 + ty * 2 + r;
#pragma unroll
    for (int u4 = 0; u4 < 4; ++u4) {
      int ol = tx * 4 + u4;                       // local o within half
      int u = pair * 64 + ol;
      *(unsigned int*)(outbuf + chat_byte(bb, otile, u, esz)) =
          packbf(accR[r][u4], accI[r][u4]);
    }
  }
}

// ---------------------------------------------------------------------------
// K3: fused Legendre synthesis + inverse DFT + bias. Block=(b, o-half):
// 128 blocks x 512 thr. Stages its chat copy (128-B runs, uint4) + stb into
// LDS, then barrier-free. Thread=(j, 2 o) x 2 sequential units; phase B fully
// unrolled with literal twiddles (zero twiddle registers / LDS).
// ---------------------------------------------------------------------------
__global__ __launch_bounds__(512) void k_bwd(char* __restrict__ outbuf,
                                             const void* __restrict__ biasv,
                                             const void* __restrict__ xin) {
  const int fp32m = detect_fp32(xin);
  const int esz = fp32m ? 4 : 2;
  __shared__ __align__(16) unsigned int chs[NPAIR * 64];   // [pair][ol] re|im bf16
  __shared__ float stb[NPAIR * 32];                        // [pair][j]
  const int b = blockIdx.x >> 1, oh = blockIdx.x & 1;
  const int t = threadIdx.x;
  for (int i = t; i < NPAIR * 16; i += 512)                // 2176 uint4
    ((uint4*)chs)[i] = *(const uint4*)(outbuf + comb_byte(b, i >> 3, oh, esz, (i & 7) * 4));
  for (int i = t; i < NPAIR * 32; i += 512) stb[i] = g_stab[i];
  const int j = t >> 4, ou = t & 15;
  __syncthreads();

  DEF_TRIG;
  for (int un = 0; un < 2; ++un) {
    const int ol = ou * 2 + un * 32;                       // local o (even)
    const int o = oh * 64 + ol;
    float bv0 = fp32m ? ((const float*)biasv)[o]
                      : us2f((unsigned int)((const unsigned short*)biasv)[o]);
    float bv1 = fp32m ? ((const float*)biasv)[o + 1]
                      : us2f((unsigned int)((const unsigned short*)biasv)[o + 1]);
    // phase A: G[m] for the 2 o's
    float Gr0[16], Gi0[16], Gr1[16], Gi1[16];
#pragma unroll
    for (int mm = 0; mm < 16; ++mm) { Gr0[mm]=0.f; Gi0[mm]=0.f; Gr1[mm]=0.f; Gi1[mm]=0.f; }
    int pair = 0;
#pragma unroll
    for (int mm = 0; mm < 16; ++mm) {
#pragma unroll
      for (int l = mm; l < 16; ++l) {
        float s = stb[pair * 32 + j];
        uint2 cv = *(const uint2*)&chs[pair * 64 + ol];
        Gr0[mm] += s * lo_f(cv.x); Gi0[mm] += s * hi_f(cv.x);
        Gr1[mm] += s * lo_f(cv.y); Gi1[mm] += s * hi_f(cv.y);
        ++pair;
      }
    }
    // phase B: inverse DFT, literal twiddles, p<->32-p symmetry
#pragma unroll
    for (int pp = 0; pp <= 16; ++pp) {
      float A0 = 0.f, B0 = 0.f, A1 = 0.f, B1 = 0.f;
#pragma unroll
      for (int mm = 0; mm < 16; ++mm) {
        A0 += Gr0[mm] * CT[(mm * pp) & 31]; B0 += Gi0[mm] * ST[(mm * pp) & 31];
        A1 += Gr1[mm] * CT[(mm * pp) & 31]; B1 += Gi1[mm] * ST[(mm * pp) & 31];
      }
      int p2 = (32 - pp) & 31;
      size_t e1 = (size_t)b * 131072 + (size_t)(j * 32 + pp) * 128 + o;
      size_t e2 = (size_t)b * 131072 + (size_t)(j * 32 + p2) * 128 + o;
      if (fp32m) {
        *(float2*)(outbuf + e1 * 4) = make_float2(bv0 + A0 - B0, bv1 + A1 - B1);
        *(float2*)(outbuf + e2 * 4) = make_float2(bv0 + A0 + B0, bv1 + A1 + B1);
      } else {
        *(unsigned int*)(outbuf + e1 * 2) = packbf(bv0 + A0 - B0, bv1 + A1 - B1);
        *(unsigned int*)(outbuf + e2 * 2) = packbf(bv0 + A0 + B0, bv1 + A1 + B1);
      }
    }
  }
}

// ---------------------------------------------------------------------------
extern "C" void kernel_launch(void* const* d_in, const int* in_sizes, int n_in,
                              void* d_out, int out_size, void* d_ws, size_t ws_size,
                              hipStream_t stream) {
  const void* xin  = d_in[0];   // (64,32,32,128) fp32 or bf16 (auto-detected)
  const void* W    = d_in[1];   // (128,16,128)
  const void* bias = d_in[2];   // (128)
  char* out = (char*)d_out;

  hipLaunchKernelGGL(k_init, dim3(NPAIR), dim3(32),  0, stream);
  hipLaunchKernelGGL(k_fwd,  dim3(512),   dim3(256), 0, stream, xin, out);
  hipLaunchKernelGGL(k_chan, dim3(544),   dim3(256), 0, stream, out, W, xin);
  hipLaunchKernelGGL(k_bwd,  dim3(128),   dim3(512), 0, stream, out, bias, xin);
}

// Round 10
// 143.508 us; speedup vs baseline: 1.9304x; 1.4926x over previous
//
#include <hip/hip_runtime.h>
#include <hip/hip_bf16.h>
#include <math.h>

// SphConv: B=64, n=32, C_in=C_out=128, L=16, (l,m) pairs l>=m: 136.
// Intermediates live inside d_out:
//  chat(b,oq):  u = pair*32 + ol (ol in [0,32)), rows s in [0, 544/esz),
//               column strip = o-quarter oq (32 elements wide).
//  coef(b,h):   u = pair*64 + cl (cl in [0,64)), rows s in [544/esz, 1088/esz),
//               column strip = c-half h (64 elements wide).
// k_bwd block (b,oq) reads only chat(b,oq) -> read-set inside own write region.
// dtype (fp32 vs bf16) detected from data (deterministic -> graph-safe).

#define NPAIR 136

static __device__ __forceinline__ float us2f(unsigned int u) {
  union { unsigned int i; float f; } v; v.i = u << 16; return v.f;
}
static __device__ __forceinline__ unsigned short f2us(float f) {
  __hip_bfloat16 h = __float2bfloat16(f);
  return *(unsigned short*)&h;
}
static __device__ __forceinline__ float lo_f(unsigned int pk) {
  union { unsigned int i; float f; } v; v.i = pk << 16; return v.f;
}
static __device__ __forceinline__ float hi_f(unsigned int pk) {
  union { unsigned int i; float f; } v; v.i = pk & 0xffff0000u; return v.f;
}
static __device__ __forceinline__ unsigned int packbf(float a, float b) {
  return (unsigned int)f2us(a) | ((unsigned int)f2us(b) << 16);
}

__device__ __align__(16) unsigned short g_atab_h[NPAIR * 32]; // bf16 Q*wj
__device__ __align__(16) float          g_stab[NPAIR * 32];   // fp32 Q*scale*(m?2:1)

static __device__ __forceinline__ int detect_fp32(const void* xin) {
  const unsigned short* u = (const unsigned short*)xin;
  int lane = threadIdx.x & 63;
  int big = 0;
#pragma unroll
  for (int q = 0; q < 4; ++q) {
    float v = us2f((unsigned int)u[lane * 8 + q * 2]);
    if (!(fabsf(v) <= 1e3f)) big = 1;
  }
  unsigned long long mask = __ballot(big);
  return (__popcll(mask) >= 16) ? 1 : 0;
}

// chat quarter: 4352 uints per (b,oq); wpr = 8*esz uints per 128-elem row.
static __device__ __forceinline__ size_t chat_q_byte(int b, int oq, int u, int esz) {
  int wpr = 8 * esz;
  int s = u / wpr, w = u % wpr;
  return ((size_t)b * 131072 + (size_t)s * 128 + oq * 32) * (size_t)esz + (size_t)w * 4;
}
// coef half: 8704 uints per (b,h); wpr = 16*esz; rows start at 544/esz.
static __device__ __forceinline__ size_t coef_byte(int b, int h, int u, int esz) {
  int wpr = 16 * esz;
  int s = 544 / esz + u / wpr, w = u % wpr;
  return ((size_t)b * 131072 + (size_t)s * 128 + h * 64) * (size_t)esz + (size_t)w * 4;
}

// 32-pt DFT trig tables, cos/sin(2*pi*k/32) — compile-time indices only
#define DEF_TRIG \
  constexpr float CT[32] = { \
    1.0f, 0.98078528f, 0.92387953f, 0.83146961f, 0.70710678f, 0.55557023f, \
    0.38268343f, 0.19509032f, 0.0f, -0.19509032f, -0.38268343f, -0.55557023f, \
    -0.70710678f, -0.83146961f, -0.92387953f, -0.98078528f, -1.0f, \
    -0.98078528f, -0.92387953f, -0.83146961f, -0.70710678f, -0.55557023f, \
    -0.38268343f, -0.19509032f, 0.0f, 0.19509032f, 0.38268343f, 0.55557023f, \
    0.70710678f, 0.83146961f, 0.92387953f, 0.98078528f }; \
  constexpr float ST[32] = { \
    0.0f, 0.19509032f, 0.38268343f, 0.55557023f, 0.70710678f, 0.83146961f, \
    0.92387953f, 0.98078528f, 1.0f, 0.98078528f, 0.92387953f, 0.83146961f, \
    0.70710678f, 0.55557023f, 0.38268343f, 0.19509032f, 0.0f, \
    -0.19509032f, -0.38268343f, -0.55557023f, -0.70710678f, -0.83146961f, \
    -0.92387953f, -0.98078528f, -1.0f, -0.98078528f, -0.92387953f, \
    -0.83146961f, -0.70710678f, -0.55557023f, -0.38268343f, -0.19509032f }

// ---------------------------------------------------------------------------
// K0: tables. One block per (l,m) pair x 32 j.
// ---------------------------------------------------------------------------
__global__ void k_init() {
  const int pair = blockIdx.x, j = threadIdx.x;
  int m = 0;
#pragma unroll
  for (int mm = 1; mm < 16; ++mm) {
    int off = mm * 16 - (mm * (mm - 1)) / 2;
    if (off <= pair) m = mm;
  }
  const int l = m + (pair - (m * 16 - (m * (m - 1)) / 2));
  double theta = M_PI * (j + 0.5) / 32.0;
  double x = cos(theta), sx = sin(theta);
  double wj = sx * (M_PI / 32.0) * (2.0 * M_PI / 32.0);
  double pmm = 1.0;
  for (int k = 1; k <= m; ++k) pmm *= -(2.0 * k - 1.0) * sx;
  double p = pmm, pl1 = 0.0, pl2 = 0.0;
  for (int ll = m; ll <= l; ++ll) {
    if (ll == m)          p = pmm;
    else if (ll == m + 1) p = (2.0 * m + 1.0) * x * pmm;
    else                  p = ((2.0 * ll - 1.0) * x * pl1 - (double)(ll + m - 1) * pl2) / (double)(ll - m);
    pl2 = pl1; pl1 = p;
  }
  double r = 1.0;
  for (int k = l - m + 1; k <= l + m; ++k) r *= (double)k;   // (l+m)!/(l-m)!
  double Nlm = sqrt((2.0 * l + 1.0) / (4.0 * M_PI) / r);
  g_atab_h[pair * 32 + j] = f2us((float)(Nlm * p * wj));
  g_stab[pair * 32 + j] = (float)(Nlm * p * (2.0 * M_PI * sqrt(4.0 * M_PI / (2.0 * l + 1.0)))
                                  * (m ? 2.0 : 1.0));
}

// ---------------------------------------------------------------------------
// K1: fused FFT(phi) + Legendre analysis -> coef. 512 blocks x 512 thr,
// block=(b, 16-ch group), XCD-swizzled. Phase 1: ONE (j,c) DFT per thread
// (~40 live floats). Phase 2: (m,c,j-half), F=4 uint4, shfl_xor combine.
// ---------------------------------------------------------------------------
__global__ __launch_bounds__(512) void k_fwd(const void* __restrict__ xin,
                                             char* __restrict__ outbuf) {
  const int fp32m = detect_fp32(xin);
  const int esz = fp32m ? 4 : 2;
  __shared__ __align__(16) unsigned short xs[32 * 520];    // [p][j*16+c]
  __shared__ __align__(16) unsigned int   fsp[256 * 36];   // [(m*16+c)][j] re|im bf16
  __shared__ __align__(16) unsigned short at[NPAIR * 32];  // atab bf16
  const int blk = blockIdx.x;
  const int b = (blk & 7) | ((blk >> 6) << 3);             // same-b -> same XCD
  const int cq = (blk >> 3) & 7;                           // 16-channel group
  const int t = threadIdx.x;
  for (int i = t; i < NPAIR * 32 / 8; i += 512)            // 544 x uint4
    ((uint4*)at)[i] = ((const uint4*)g_atab_h)[i];
  if (fp32m) {
    const float* xf = (const float*)xin;
#pragma unroll
    for (int it = 0; it < 8; ++it) {
      int i = t + it * 512;                                // [0,4096)
      int jp = i >> 2, q = i & 3;
      float4 v = *(const float4*)(xf + ((size_t)b * 1024 + jp) * 128 + cq * 16 + q * 4);
      int p = jp & 31, j = jp >> 5;
      *(uint2*)&xs[p * 520 + j * 16 + q * 4] =
          make_uint2(packbf(v.x, v.y), packbf(v.z, v.w));
    }
  } else {
    const unsigned short* xh = (const unsigned short*)xin;
#pragma unroll
    for (int it = 0; it < 4; ++it) {
      int i = t + it * 512;                                // [0,2048)
      int jp = i >> 1, hf = i & 1;
      uint4 v = *(const uint4*)(xh + ((size_t)b * 1024 + jp) * 128 + cq * 16 + hf * 8);
      int p = jp & 31, j = jp >> 5;
      *(uint4*)&xs[p * 520 + j * 16 + hf * 8] = v;
    }
  }
  __syncthreads();
  {   // phase 1: one 32-pt real DFT per thread. thread = (j, c).
    DEF_TRIG;
    const int j = t >> 4, c = t & 15, rb = j * 16 + c;
    float x0  = us2f((unsigned int)xs[rb]);
    float x16 = us2f((unsigned int)xs[16 * 520 + rb]);
    float sp[16], dm[16];
#pragma unroll
    for (int p = 1; p <= 15; ++p) {
      float a  = us2f((unsigned int)xs[p * 520 + rb]);
      float bq = us2f((unsigned int)xs[(32 - p) * 520 + rb]);
      sp[p] = a + bq; dm[p] = a - bq;
    }
#pragma unroll
    for (int mi = 0; mi < 16; ++mi) {
      float re = x0 + ((mi & 1) ? -x16 : x16);
      float im = 0.f;
#pragma unroll
      for (int p = 1; p <= 15; ++p) {
        re += sp[p] * CT[(mi * p) & 31];
        im -= dm[p] * ST[(mi * p) & 31];
      }
      fsp[(mi * 16 + c) * 36 + j] = packbf(re, im);
    }
  }
  __syncthreads();
  {   // phase 2: quadrature. thread = (m, c, jh); F = 4 uint4 (16 regs).
    const int m = t >> 5, c = (t >> 1) & 15, jh = t & 1;
    const int cg = cq * 16 + c, h = cg >> 6, cl = cg & 63;
    const int base = m * 16 - (m * (m - 1)) / 2;
    uint4 F[4];
#pragma unroll
    for (int q = 0; q < 4; ++q)
      F[q] = *(const uint4*)&fsp[(m * 16 + c) * 36 + jh * 16 + q * 4];
    for (int l = m; l < 16; ++l) {
      int pair = base + (l - m);
      float sr = 0.f, si = 0.f;
#pragma unroll
      for (int q = 0; q < 2; ++q) {
        uint4 a = *(const uint4*)&at[pair * 32 + jh * 16 + q * 8];
        float a0 = us2f(a.x & 0xffff), a1 = us2f(a.x >> 16);
        float a2 = us2f(a.y & 0xffff), a3 = us2f(a.y >> 16);
        float a4 = us2f(a.z & 0xffff), a5 = us2f(a.z >> 16);
        float a6 = us2f(a.w & 0xffff), a7 = us2f(a.w >> 16);
        uint4 f0 = F[2 * q], f1 = F[2 * q + 1];
        sr += a0 * lo_f(f0.x) + a1 * lo_f(f0.y) + a2 * lo_f(f0.z) + a3 * lo_f(f0.w)
            + a4 * lo_f(f1.x) + a5 * lo_f(f1.y) + a6 * lo_f(f1.z) + a7 * lo_f(f1.w);
        si += a0 * hi_f(f0.x) + a1 * hi_f(f0.y) + a2 * hi_f(f0.z) + a3 * hi_f(f0.w)
            + a4 * hi_f(f1.x) + a5 * hi_f(f1.y) + a6 * hi_f(f1.z) + a7 * hi_f(f1.w);
      }
      sr += __shfl_xor(sr, 1, 64);
      si += __shfl_xor(si, 1, 64);
      if (jh == 0) {
        int u = pair * 64 + cl;
        *(unsigned int*)(outbuf + coef_byte(b, h, u, esz)) = packbf(sr, si);
      }
    }
  }
}

// ---------------------------------------------------------------------------
// K2: channel GEMM. Block=(pair, b-half, o-half): M=32(b), N=64(o), K=128(c),
// re+im together. 544 blocks x 256 thr.
// ---------------------------------------------------------------------------
__global__ __launch_bounds__(256) void k_chan(char* __restrict__ outbuf,
                                              const void* __restrict__ Wv,
                                              const void* __restrict__ xin) {
  const int fp32m = detect_fp32(xin);
  const int esz = fp32m ? 4 : 2;
  const int pair = blockIdx.x >> 2;
  const int bh = (blockIdx.x >> 1) & 1, otile = blockIdx.x & 1;
  int m = 0;
#pragma unroll
  for (int mm = 1; mm < 16; ++mm) {
    int off = mm * 16 - (mm * (mm - 1)) / 2;
    if (off <= pair) m = mm;
  }
  const int l = m + (pair - (m * 16 - (m * (m - 1)) / 2));
  __shared__ float Xr[32 * 132], Xi[32 * 132];   // [b'][c]
  __shared__ __align__(16) float Wsh[32 * 68];   // [kk][o]
  const int t = threadIdx.x;
  for (int i = t; i < 4096; i += 256) {
    int bl = i >> 7, c = i & 127;
    int u = pair * 64 + (c & 63), h = c >> 6;
    unsigned int pk = *(const unsigned int*)(outbuf + coef_byte(bh * 32 + bl, h, u, esz));
    Xr[bl * 132 + c] = lo_f(pk);
    Xi[bl * 132 + c] = hi_f(pk);
  }
  const int tx = t & 15, ty = t >> 4;
  float accR[2][4] = {}, accI[2][4] = {};
  for (int kc = 0; kc < 4; ++kc) {
    __syncthreads();
    {
      int o = t & 63, k0 = t >> 6;
#pragma unroll
      for (int it = 0; it < 8; ++it) {
        int kk = k0 + it * 4;
        size_t widx = (size_t)(kc * 32 + kk) * 2048 + l * 128 + otile * 64 + o;
        Wsh[kk * 68 + o] = fp32m ? ((const float*)Wv)[widx]
                                 : us2f((unsigned int)((const unsigned short*)Wv)[widx]);
      }
    }
    __syncthreads();
#pragma unroll
    for (int k = 0; k < 32; ++k) {
      int K = kc * 32 + k;
      float r0 = Xr[(ty * 2 + 0) * 132 + K], r1 = Xr[(ty * 2 + 1) * 132 + K];
      float i0 = Xi[(ty * 2 + 0) * 132 + K], i1 = Xi[(ty * 2 + 1) * 132 + K];
      float4 w = *(const float4*)&Wsh[k * 68 + tx * 4];
      accR[0][0] += r0*w.x; accR[0][1] += r0*w.y; accR[0][2] += r0*w.z; accR[0][3] += r0*w.w;
      accR[1][0] += r1*w.x; accR[1][1] += r1*w.y; accR[1][2] += r1*w.z; accR[1][3] += r1*w.w;
      accI[0][0] += i0*w.x; accI[0][1] += i0*w.y; accI[0][2] += i0*w.z; accI[0][3] += i0*w.w;
      accI[1][0] += i1*w.x; accI[1][1] += i1*w.y; accI[1][2] += i1*w.z; accI[1][3] += i1*w.w;
    }
  }
#pragma unroll
  for (int r = 0; r < 2; ++r) {
    int bb = bh * 32 + ty * 2 + r;
#pragma unroll
    for (int u4 = 0; u4 < 4; ++u4) {
      int o = otile * 64 + tx * 4 + u4;
      int u = pair * 32 + (o & 31);
      *(unsigned int*)(outbuf + chat_q_byte(bb, o >> 5, u, esz)) =
          packbf(accR[r][u4], accI[r][u4]);
    }
  }
}

// ---------------------------------------------------------------------------
// K3: fused Legendre synthesis + inverse DFT + bias. Block=(b, o-quarter):
// 256 blocks x 512 thr. Thread=(j, one o) x 2 NON-UNROLLED units -> 32 G
// floats live. Barrier-free after staging; literal twiddles in phase B.
// ---------------------------------------------------------------------------
__global__ __launch_bounds__(512) void k_bwd(char* __restrict__ outbuf,
                                             const void* __restrict__ biasv,
                                             const void* __restrict__ xin) {
  const int fp32m = detect_fp32(xin);
  const int esz = fp32m ? 4 : 2;
  __shared__ __align__(16) unsigned int chs[NPAIR * 32];   // [pair][ol] re|im bf16
  __shared__ float stb[NPAIR * 32];                        // [pair][j]
  const int b = blockIdx.x >> 2, oq = blockIdx.x & 3;
  const int t = threadIdx.x;
  for (int i = t; i < NPAIR * 8; i += 512)                 // 1088 uint4
    ((uint4*)chs)[i] = *(const uint4*)(outbuf + chat_q_byte(b, oq, i * 4, esz));
  for (int i = t; i < NPAIR * 32; i += 512) stb[i] = g_stab[i];
  const int j = t >> 4, ou = t & 15;
  __syncthreads();

  DEF_TRIG;
#pragma unroll 1
  for (int un = 0; un < 2; ++un) {
    const int ol = ou + un * 16;                           // local o in quarter
    const int o = oq * 32 + ol;
    float bv = fp32m ? ((const float*)biasv)[o]
                     : us2f((unsigned int)((const unsigned short*)biasv)[o]);
    // phase A: G[m] (16 cplx = 32 floats)
    float Gr[16], Gi[16];
#pragma unroll
    for (int mm = 0; mm < 16; ++mm) { Gr[mm] = 0.f; Gi[mm] = 0.f; }
    int pair = 0;
#pragma unroll
    for (int mm = 0; mm < 16; ++mm) {
#pragma unroll
      for (int l = mm; l < 16; ++l) {
        float s = stb[pair * 32 + j];
        unsigned int cv = chs[pair * 32 + ol];
        Gr[mm] += s * lo_f(cv);
        Gi[mm] += s * hi_f(cv);
        ++pair;
      }
    }
    // phase B: inverse DFT, literal twiddles, p<->32-p symmetry
#pragma unroll
    for (int pp = 0; pp <= 16; ++pp) {
      float A = 0.f, Bv = 0.f;
#pragma unroll
      for (int mm = 0; mm < 16; ++mm) {
        A  += Gr[mm] * CT[(mm * pp) & 31];
        Bv += Gi[mm] * ST[(mm * pp) & 31];
      }
      int p2 = (32 - pp) & 31;
      size_t e1 = (size_t)b * 131072 + (size_t)(j * 32 + pp) * 128 + o;
      size_t e2 = (size_t)b * 131072 + (size_t)(j * 32 + p2) * 128 + o;
      if (fp32m) {
        *(float*)(outbuf + e1 * 4) = bv + A - Bv;
        *(float*)(outbuf + e2 * 4) = bv + A + Bv;
      } else {
        *(unsigned short*)(outbuf + e1 * 2) = f2us(bv + A - Bv);
        *(unsigned short*)(outbuf + e2 * 2) = f2us(bv + A + Bv);
      }
    }
  }
}

// ---------------------------------------------------------------------------
extern "C" void kernel_launch(void* const* d_in, const int* in_sizes, int n_in,
                              void* d_out, int out_size, void* d_ws, size_t ws_size,
                              hipStream_t stream) {
  const void* xin  = d_in[0];   // (64,32,32,128) fp32 or bf16 (auto-detected)
  const void* W    = d_in[1];   // (128,16,128)
  const void* bias = d_in[2];   // (128)
  char* out = (char*)d_out;

  hipLaunchKernelGGL(k_init, dim3(NPAIR), dim3(32),  0, stream);
  hipLaunchKernelGGL(k_fwd,  dim3(512),   dim3(512), 0, stream, xin, out);
  hipLaunchKernelGGL(k_chan, dim3(544),   dim3(256), 0, stream, out, W, xin);
  hipLaunchKernelGGL(k_bwd,  dim3(256),   dim3(512), 0, stream, out, bias, xin);
}

// Round 11
// 135.004 us; speedup vs baseline: 2.0520x; 1.0630x over previous
//
#include <hip/hip_runtime.h>
#include <hip/hip_bf16.h>
#include <math.h>

// SphConv: B=64, n=32, C_in=C_out=128, L=16, (l,m) pairs l>=m: 136.
// Intermediates live inside d_out (chat per (b,o-quarter) strip, coef per
// (b,c-half) strip) — every k_bwd block's read-set is inside its own write
// region. dtype (fp32 vs bf16) detected from data (deterministic).
// k_chan uses MFMA 16x16x32 bf16 (coef/chat are bf16-packed anyway).

#define NPAIR 136

typedef __attribute__((ext_vector_type(8))) short short8;
typedef __attribute__((ext_vector_type(4))) float f32x4;
#define MFMA16(A, B, C) __builtin_amdgcn_mfma_f32_16x16x32_bf16(A, B, C, 0, 0, 0)

static __device__ __forceinline__ float us2f(unsigned int u) {
  union { unsigned int i; float f; } v; v.i = u << 16; return v.f;
}
static __device__ __forceinline__ unsigned short f2us(float f) {
  __hip_bfloat16 h = __float2bfloat16(f);
  return *(unsigned short*)&h;
}
static __device__ __forceinline__ float lo_f(unsigned int pk) {
  union { unsigned int i; float f; } v; v.i = pk << 16; return v.f;
}
static __device__ __forceinline__ float hi_f(unsigned int pk) {
  union { unsigned int i; float f; } v; v.i = pk & 0xffff0000u; return v.f;
}
static __device__ __forceinline__ unsigned int packbf(float a, float b) {
  return (unsigned int)f2us(a) | ((unsigned int)f2us(b) << 16);
}

__device__ __align__(16) unsigned short g_atab_h[NPAIR * 32]; // bf16 Q*wj
__device__ __align__(16) float          g_stab[NPAIR * 32];   // fp32 Q*scale*(m?2:1)

static __device__ __forceinline__ int detect_fp32(const void* xin) {
  const unsigned short* u = (const unsigned short*)xin;
  int lane = threadIdx.x & 63;
  int big = 0;
#pragma unroll
  for (int q = 0; q < 4; ++q) {
    float v = us2f((unsigned int)u[lane * 8 + q * 2]);
    if (!(fabsf(v) <= 1e3f)) big = 1;
  }
  unsigned long long mask = __ballot(big);
  return (__popcll(mask) >= 16) ? 1 : 0;
}

// chat quarter: 4352 uints per (b,oq); wpr = 8*esz uints per 128-elem row.
static __device__ __forceinline__ size_t chat_q_byte(int b, int oq, int u, int esz) {
  int wpr = 8 * esz;
  int s = u / wpr, w = u % wpr;
  return ((size_t)b * 131072 + (size_t)s * 128 + oq * 32) * (size_t)esz + (size_t)w * 4;
}
// coef half: 8704 uints per (b,h); wpr = 16*esz; rows start at 544/esz.
static __device__ __forceinline__ size_t coef_byte(int b, int h, int u, int esz) {
  int wpr = 16 * esz;
  int s = 544 / esz + u / wpr, w = u % wpr;
  return ((size_t)b * 131072 + (size_t)s * 128 + h * 64) * (size_t)esz + (size_t)w * 4;
}

// 32-pt DFT trig tables, cos/sin(2*pi*k/32) — compile-time indices only
#define DEF_TRIG \
  constexpr float CT[32] = { \
    1.0f, 0.98078528f, 0.92387953f, 0.83146961f, 0.70710678f, 0.55557023f, \
    0.38268343f, 0.19509032f, 0.0f, -0.19509032f, -0.38268343f, -0.55557023f, \
    -0.70710678f, -0.83146961f, -0.92387953f, -0.98078528f, -1.0f, \
    -0.98078528f, -0.92387953f, -0.83146961f, -0.70710678f, -0.55557023f, \
    -0.38268343f, -0.19509032f, 0.0f, 0.19509032f, 0.38268343f, 0.55557023f, \
    0.70710678f, 0.83146961f, 0.92387953f, 0.98078528f }; \
  constexpr float ST[32] = { \
    0.0f, 0.19509032f, 0.38268343f, 0.55557023f, 0.70710678f, 0.83146961f, \
    0.92387953f, 0.98078528f, 1.0f, 0.98078528f, 0.92387953f, 0.83146961f, \
    0.70710678f, 0.55557023f, 0.38268343f, 0.19509032f, 0.0f, \
    -0.19509032f, -0.38268343f, -0.55557023f, -0.70710678f, -0.83146961f, \
    -0.92387953f, -0.98078528f, -1.0f, -0.98078528f, -0.92387953f, \
    -0.83146961f, -0.70710678f, -0.55557023f, -0.38268343f, -0.19509032f }

// ---------------------------------------------------------------------------
// K0: tables. One block per (l,m) pair x 32 j.
// ---------------------------------------------------------------------------
__global__ void k_init() {
  const int pair = blockIdx.x, j = threadIdx.x;
  int m = 0;
#pragma unroll
  for (int mm = 1; mm < 16; ++mm) {
    int off = mm * 16 - (mm * (mm - 1)) / 2;
    if (off <= pair) m = mm;
  }
  const int l = m + (pair - (m * 16 - (m * (m - 1)) / 2));
  double theta = M_PI * (j + 0.5) / 32.0;
  double x = cos(theta), sx = sin(theta);
  double wj = sx * (M_PI / 32.0) * (2.0 * M_PI / 32.0);
  double pmm = 1.0;
  for (int k = 1; k <= m; ++k) pmm *= -(2.0 * k - 1.0) * sx;
  double p = pmm, pl1 = 0.0, pl2 = 0.0;
  for (int ll = m; ll <= l; ++ll) {
    if (ll == m)          p = pmm;
    else if (ll == m + 1) p = (2.0 * m + 1.0) * x * pmm;
    else                  p = ((2.0 * ll - 1.0) * x * pl1 - (double)(ll + m - 1) * pl2) / (double)(ll - m);
    pl2 = pl1; pl1 = p;
  }
  double r = 1.0;
  for (int k = l - m + 1; k <= l + m; ++k) r *= (double)k;   // (l+m)!/(l-m)!
  double Nlm = sqrt((2.0 * l + 1.0) / (4.0 * M_PI) / r);
  g_atab_h[pair * 32 + j] = f2us((float)(Nlm * p * wj));
  g_stab[pair * 32 + j] = (float)(Nlm * p * (2.0 * M_PI * sqrt(4.0 * M_PI / (2.0 * l + 1.0)))
                                  * (m ? 2.0 : 1.0));
}

// ---------------------------------------------------------------------------
// K1: fused FFT(phi) + Legendre analysis -> coef. 1024 blocks x 256 thr,
// block=(b, 8-ch group), XCD-swizzled. LDS 35 KB -> 4 blocks/CU.
// Phase 1: one (j,c) DFT per thread. Phase 2: (m,c,jh), atab from global.
// ---------------------------------------------------------------------------
__global__ __launch_bounds__(256) void k_fwd(const void* __restrict__ xin,
                                             char* __restrict__ outbuf) {
  const int fp32m = detect_fp32(xin);
  const int esz = fp32m ? 4 : 2;
  __shared__ __align__(16) unsigned short xs[32 * 264];    // [p][j*8+c]
  __shared__ __align__(16) unsigned int   fsp[128 * 36];   // [(m*8+c)][j] re|im bf16
  const int blk = blockIdx.x;
  const int b = (blk & 7) | (((blk >> 7) & 7) << 3);       // same-b -> same XCD
  const int cq = (blk >> 3) & 15;                          // 8-channel group
  const int t = threadIdx.x;
  if (fp32m) {
    const float* xf = (const float*)xin;
#pragma unroll
    for (int it = 0; it < 8; ++it) {
      int i = t + it * 256;                                // [0,2048)
      int s = i >> 1, hf = i & 1;
      float4 v = *(const float4*)(xf + ((size_t)b * 1024 + s) * 128 + cq * 8 + hf * 4);
      int p = s & 31, j = s >> 5;
      *(uint2*)&xs[p * 264 + j * 8 + hf * 4] = make_uint2(packbf(v.x, v.y), packbf(v.z, v.w));
    }
  } else {
    const unsigned short* xh = (const unsigned short*)xin;
#pragma unroll
    for (int it = 0; it < 4; ++it) {
      int s = t + it * 256;                                // [0,1024)
      uint4 v = *(const uint4*)(xh + ((size_t)b * 1024 + s) * 128 + cq * 8);
      int p = s & 31, j = s >> 5;
      *(uint4*)&xs[p * 264 + j * 8] = v;
    }
  }
  __syncthreads();
  {   // phase 1: one 32-pt real DFT per thread. thread = (j, c).
    DEF_TRIG;
    const int j = t >> 3, c = t & 7, rb = j * 8 + c;
    float x0  = us2f((unsigned int)xs[rb]);
    float x16 = us2f((unsigned int)xs[16 * 264 + rb]);
    float sp[16], dm[16];
#pragma unroll
    for (int p = 1; p <= 15; ++p) {
      float a  = us2f((unsigned int)xs[p * 264 + rb]);
      float bq = us2f((unsigned int)xs[(32 - p) * 264 + rb]);
      sp[p] = a + bq; dm[p] = a - bq;
    }
#pragma unroll
    for (int mi = 0; mi < 16; ++mi) {
      float re = x0 + ((mi & 1) ? -x16 : x16);
      float im = 0.f;
#pragma unroll
      for (int p = 1; p <= 15; ++p) {
        re += sp[p] * CT[(mi * p) & 31];
        im -= dm[p] * ST[(mi * p) & 31];
      }
      fsp[(mi * 8 + c) * 36 + j] = packbf(re, im);
    }
  }
  __syncthreads();
  {   // phase 2: quadrature. thread = (m, c, jh); F = 4 uint4; atab global.
    const int m = t >> 4, c = (t >> 1) & 7, jh = t & 1;
    const int cg = cq * 8 + c, h = cg >> 6, cl = cg & 63;
    const int base = m * 16 - (m * (m - 1)) / 2;
    uint4 F[4];
#pragma unroll
    for (int q = 0; q < 4; ++q)
      F[q] = *(const uint4*)&fsp[(m * 8 + c) * 36 + jh * 16 + q * 4];
    for (int l = m; l < 16; ++l) {
      int pair = base + (l - m);
      float sr = 0.f, si = 0.f;
#pragma unroll
      for (int q = 0; q < 2; ++q) {
        uint4 a = *(const uint4*)&g_atab_h[pair * 32 + jh * 16 + q * 8];
        float a0 = us2f(a.x & 0xffff), a1 = us2f(a.x >> 16);
        float a2 = us2f(a.y & 0xffff), a3 = us2f(a.y >> 16);
        float a4 = us2f(a.z & 0xffff), a5 = us2f(a.z >> 16);
        float a6 = us2f(a.w & 0xffff), a7 = us2f(a.w >> 16);
        uint4 f0 = F[2 * q], f1 = F[2 * q + 1];
        sr += a0 * lo_f(f0.x) + a1 * lo_f(f0.y) + a2 * lo_f(f0.z) + a3 * lo_f(f0.w)
            + a4 * lo_f(f1.x) + a5 * lo_f(f1.y) + a6 * lo_f(f1.z) + a7 * lo_f(f1.w);
        si += a0 * hi_f(f0.x) + a1 * hi_f(f0.y) + a2 * hi_f(f0.z) + a3 * hi_f(f0.w)
            + a4 * hi_f(f1.x) + a5 * hi_f(f1.y) + a6 * hi_f(f1.z) + a7 * hi_f(f1.w);
      }
      sr += __shfl_xor(sr, 1, 64);
      si += __shfl_xor(si, 1, 64);
      if (jh == 0) {
        int u = pair * 64 + cl;
        *(unsigned int*)(outbuf + coef_byte(b, h, u, esz)) = packbf(sr, si);
      }
    }
  }
}

// ---------------------------------------------------------------------------
// K2: channel GEMM via MFMA 16x16x32 bf16. Block=(pair, b-half, o-half):
// M=32(b), N=64(o), K=128(c), re+im sharing W fragments. 544 blocks x 256 thr.
// A[m=lane&15][k=quad*8+j], B[k=quad*8+j][n=lane&15], D col=lane&15,
// row=quad*4+reg (verified gfx950 mappings).
// ---------------------------------------------------------------------------
__global__ __launch_bounds__(256) void k_chan(char* __restrict__ outbuf,
                                              const void* __restrict__ Wv,
                                              const void* __restrict__ xin) {
  const int fp32m = detect_fp32(xin);
  const int esz = fp32m ? 4 : 2;
  const int pair = blockIdx.x >> 2;
  const int bh = (blockIdx.x >> 1) & 1, otile = blockIdx.x & 1;
  int m = 0;
#pragma unroll
  for (int mm = 1; mm < 16; ++mm) {
    int off = mm * 16 - (mm * (mm - 1)) / 2;
    if (off <= pair) m = mm;
  }
  const int l = m + (pair - (m * 16 - (m * (m - 1)) / 2));
  __shared__ __align__(16) unsigned short Xr[32 * 136];   // [b'][c] bf16
  __shared__ __align__(16) unsigned short Xi[32 * 136];
  __shared__ __align__(16) unsigned short Wt[64 * 136];   // [o'][c] bf16 (transposed)
  const int t = threadIdx.x;
  // stage coef (packed re|im uints in both modes)
  for (int i = t; i < 4096; i += 256) {
    int bl = i >> 7, c = i & 127;
    unsigned int pk = *(const unsigned int*)(outbuf +
        coef_byte(bh * 32 + bl, c >> 6, pair * 64 + (c & 63), esz));
    Xr[bl * 136 + c] = (unsigned short)(pk & 0xffff);
    Xi[bl * 136 + c] = (unsigned short)(pk >> 16);
  }
  // stage W transposed: Wt[o'][c], o' in [0,64)
  for (int i = t; i < 1024; i += 256) {
    int c = i >> 3, og = i & 7;
    size_t widx = (size_t)c * 2048 + l * 128 + otile * 64 + og * 8;
    if (fp32m) {
      const float* Wf = (const float*)Wv;
      float4 f0 = *(const float4*)(Wf + widx);
      float4 f1 = *(const float4*)(Wf + widx + 4);
      Wt[(og * 8 + 0) * 136 + c] = f2us(f0.x); Wt[(og * 8 + 1) * 136 + c] = f2us(f0.y);
      Wt[(og * 8 + 2) * 136 + c] = f2us(f0.z); Wt[(og * 8 + 3) * 136 + c] = f2us(f0.w);
      Wt[(og * 8 + 4) * 136 + c] = f2us(f1.x); Wt[(og * 8 + 5) * 136 + c] = f2us(f1.y);
      Wt[(og * 8 + 6) * 136 + c] = f2us(f1.z); Wt[(og * 8 + 7) * 136 + c] = f2us(f1.w);
    } else {
      const unsigned short* Wh = (const unsigned short*)Wv;
      uint4 v = *(const uint4*)(Wh + widx);
      Wt[(og * 8 + 0) * 136 + c] = (unsigned short)(v.x & 0xffff);
      Wt[(og * 8 + 1) * 136 + c] = (unsigned short)(v.x >> 16);
      Wt[(og * 8 + 2) * 136 + c] = (unsigned short)(v.y & 0xffff);
      Wt[(og * 8 + 3) * 136 + c] = (unsigned short)(v.y >> 16);
      Wt[(og * 8 + 4) * 136 + c] = (unsigned short)(v.z & 0xffff);
      Wt[(og * 8 + 5) * 136 + c] = (unsigned short)(v.z >> 16);
      Wt[(og * 8 + 6) * 136 + c] = (unsigned short)(v.w & 0xffff);
      Wt[(og * 8 + 7) * 136 + c] = (unsigned short)(v.w >> 16);
    }
  }
  __syncthreads();
  // MFMA: wave -> (mtile = w&1, n-group = w>>1 covering 2 n-tiles)
  const int wv = t >> 6, lane = t & 63;
  const int col = lane & 15, quad = lane >> 4;
  const int mtile = wv & 1, ng = wv >> 1;
  f32x4 accR0 = {0.f, 0.f, 0.f, 0.f}, accI0 = accR0, accR1 = accR0, accI1 = accR0;
#pragma unroll
  for (int kc = 0; kc < 4; ++kc) {
    short8 Ar = *(const short8*)&Xr[(mtile * 16 + col) * 136 + kc * 32 + quad * 8];
    short8 Ai = *(const short8*)&Xi[(mtile * 16 + col) * 136 + kc * 32 + quad * 8];
    short8 B0 = *(const short8*)&Wt[(ng * 32 + col) * 136 + kc * 32 + quad * 8];
    short8 B1 = *(const short8*)&Wt[(ng * 32 + 16 + col) * 136 + kc * 32 + quad * 8];
    accR0 = MFMA16(Ar, B0, accR0);
    accI0 = MFMA16(Ai, B0, accI0);
    accR1 = MFMA16(Ar, B1, accR1);
    accI1 = MFMA16(Ai, B1, accI1);
  }
  // epilogue: D col=lane&15, row=quad*4+reg
#pragma unroll
  for (int reg = 0; reg < 4; ++reg) {
    int bb = bh * 32 + mtile * 16 + quad * 4 + reg;
    int o0 = otile * 64 + ng * 32 + col;
    int o1 = o0 + 16;
    *(unsigned int*)(outbuf + chat_q_byte(bb, o0 >> 5, pair * 32 + (o0 & 31), esz)) =
        packbf(accR0[reg], accI0[reg]);
    *(unsigned int*)(outbuf + chat_q_byte(bb, o1 >> 5, pair * 32 + (o1 & 31), esz)) =
        packbf(accR1[reg], accI1[reg]);
  }
}

// ---------------------------------------------------------------------------
// K3: fused Legendre synthesis + inverse DFT + bias. Block=(b, o-quarter):
// 256 blocks x 512 thr. Thread=(j, one o) x 2 NON-UNROLLED units. Barrier-
// free after staging; literal twiddles in phase B. (unchanged from round 10)
// ---------------------------------------------------------------------------
__global__ __launch_bounds__(512) void k_bwd(char* __restrict__ outbuf,
                                             const void* __restrict__ biasv,
                                             const void* __restrict__ xin) {
  const int fp32m = detect_fp32(xin);
  const int esz = fp32m ? 4 : 2;
  __shared__ __align__(16) unsigned int chs[NPAIR * 32];   // [pair][ol] re|im bf16
  __shared__ float stb[NPAIR * 32];                        // [pair][j]
  const int b = blockIdx.x >> 2, oq = blockIdx.x & 3;
  const int t = threadIdx.x;
  for (int i = t; i < NPAIR * 8; i += 512)                 // 1088 uint4
    ((uint4*)chs)[i] = *(const uint4*)(outbuf + chat_q_byte(b, oq, i * 4, esz));
  for (int i = t; i < NPAIR * 32; i += 512) stb[i] = g_stab[i];
  const int j = t >> 4, ou = t & 15;
  __syncthreads();

  DEF_TRIG;
#pragma unroll 1
  for (int un = 0; un < 2; ++un) {
    const int ol = ou + un * 16;                           // local o in quarter
    const int o = oq * 32 + ol;
    float bv = fp32m ? ((const float*)biasv)[o]
                     : us2f((unsigned int)((const unsigned short*)biasv)[o]);
    float Gr[16], Gi[16];
#pragma unroll
    for (int mm = 0; mm < 16; ++mm) { Gr[mm] = 0.f; Gi[mm] = 0.f; }
    int pair = 0;
#pragma unroll
    for (int mm = 0; mm < 16; ++mm) {
#pragma unroll
      for (int l = mm; l < 16; ++l) {
        float s = stb[pair * 32 + j];
        unsigned int cv = chs[pair * 32 + ol];
        Gr[mm] += s * lo_f(cv);
        Gi[mm] += s * hi_f(cv);
        ++pair;
      }
    }
#pragma unroll
    for (int pp = 0; pp <= 16; ++pp) {
      float A = 0.f, Bv = 0.f;
#pragma unroll
      for (int mm = 0; mm < 16; ++mm) {
        A  += Gr[mm] * CT[(mm * pp) & 31];
        Bv += Gi[mm] * ST[(mm * pp) & 31];
      }
      int p2 = (32 - pp) & 31;
      size_t e1 = (size_t)b * 131072 + (size_t)(j * 32 + pp) * 128 + o;
      size_t e2 = (size_t)b * 131072 + (size_t)(j * 32 + p2) * 128 + o;
      if (fp32m) {
        *(float*)(outbuf + e1 * 4) = bv + A - Bv;
        *(float*)(outbuf + e2 * 4) = bv + A + Bv;
      } else {
        *(unsigned short*)(outbuf + e1 * 2) = f2us(bv + A - Bv);
        *(unsigned short*)(outbuf + e2 * 2) = f2us(bv + A + Bv);
      }
    }
  }
}

// ---------------------------------------------------------------------------
extern "C" void kernel_launch(void* const* d_in, const int* in_sizes, int n_in,
                              void* d_out, int out_size, void* d_ws, size_t ws_size,
                              hipStream_t stream) {
  const void* xin  = d_in[0];   // (64,32,32,128) fp32 or bf16 (auto-detected)
  const void* W    = d_in[1];   // (128,16,128)
  const void* bias = d_in[2];   // (128)
  char* out = (char*)d_out;

  hipLaunchKernelGGL(k_init, dim3(NPAIR), dim3(32),  0, stream);
  hipLaunchKernelGGL(k_fwd,  dim3(1024),  dim3(256), 0, stream, xin, out);
  hipLaunchKernelGGL(k_chan, dim3(544),   dim3(256), 0, stream, out, W, xin);
  hipLaunchKernelGGL(k_bwd,  dim3(256),   dim3(512), 0, stream, out, bias, xin);
}